// Round 4
// baseline (29146.384 us; speedup 1.0000x reference)
//
#include <hip/hip_runtime.h>

typedef short short8 __attribute__((ext_vector_type(8)));
typedef float f32x4 __attribute__((ext_vector_type(4)));

__device__ __forceinline__ unsigned short f2bf(float x) {
    unsigned int u = __float_as_uint(x);
    u += 0x7FFFu + ((u >> 16) & 1u);   // round-to-nearest-even
    return (unsigned short)(u >> 16);
}

__device__ __forceinline__ float sigmoidf_(float x) {
    return 1.0f / (1.0f + __expf(-x));
}

__device__ __forceinline__ float tanhf_(float x) {
    float ax = fabsf(x);
    float e = __expf(2.0f * ax);
    float t = 1.0f - 2.0f / (e + 1.0f);
    return copysignf(t, x);
}

// Device-scope grid barrier (generation-counter style). All 512 blocks are
// co-resident (2 blocks/CU guaranteed by __launch_bounds__(256,2) + 36KB LDS).
__device__ __forceinline__ void gridbar(unsigned* counter, unsigned* gen, unsigned nb) {
    __syncthreads();
    if (threadIdx.x == 0) {
        __threadfence();   // release all prior stores device-wide
        unsigned g = __hip_atomic_load(gen, __ATOMIC_RELAXED, __HIP_MEMORY_SCOPE_AGENT);
        unsigned a = __hip_atomic_fetch_add(counter, 1u, __ATOMIC_ACQ_REL, __HIP_MEMORY_SCOPE_AGENT);
        if (a + 1u == nb) {
            __hip_atomic_store(counter, 0u, __ATOMIC_RELAXED, __HIP_MEMORY_SCOPE_AGENT);
            __hip_atomic_fetch_add(gen, 1u, __ATOMIC_RELEASE, __HIP_MEMORY_SCOPE_AGENT);
        } else {
            while (__hip_atomic_load(gen, __ATOMIC_RELAXED, __HIP_MEMORY_SCOPE_AGENT) == g)
                __builtin_amdgcn_s_sleep(8);
        }
        __threadfence();   // acquire
    }
    __syncthreads();
}

// ---------------- packed layouts ----------------
// hP  [rg 16][kc 32][lane 64][j 8]  (lane = q*16+m holds h[rg*16+m][kc*32+q*8+j])
// WP  [ug 64][kc K/32][gate 4][lane 64][j 8]
// Every K-loop load is base + lane*16B -> one contiguous 1 KB per instruction.

// One LSTM step tile: 64 batch rows x 16 units (x4 gates).
// 4 waves K-split, 4x4 MFMA register blocking, 4-stage register pipeline,
// fp32 LDS reduction. Prefetch overruns up to 4 chunks past the slice end ->
// guard/adjacent memory required (workspace layout guarantees it).
template<int K>
__device__ __forceinline__ void lstm_tile(
    float* smem,
    int idx,
    const unsigned short* __restrict__ A1,   // hP, first K-half
    const unsigned short* __restrict__ A2,   // hP, second K-half (K==2048) or null
    const unsigned short* __restrict__ W,    // WP packed
    const float* __restrict__ bias,          // [4096]
    const float* __restrict__ xvec, int xstride,
    const float* __restrict__ Wx,            // [4096] or null
    float* __restrict__ c,                   // [256,1024] fp32 in-place
    unsigned short* __restrict__ hout,       // hP packed out
    const float* __restrict__ fcW,
    const float* __restrict__ fcb,
    float* __restrict__ yout)
{
    float* T0  = smem;                 // 64 x 68
    float* T1  = smem + 64 * 68;
    float* red = smem + 2 * 64 * 68;   // 4 x 64

    constexpr int KS = K / 4;
    constexpr int NC = KS / 32;        // chunks per wave (8 or 16)
    constexpr int KC = K / 32;
    const int tid  = threadIdx.x;
    const int lane = tid & 63;
    const int wave = tid >> 6;
    const int g  = idx >> 6;           // batch group (64 rows)
    const int ug = idx & 63;           // unit group (16 units)
    const int mb = g * 64;
    const int ub = ug * 16;

    const unsigned short* Af = (K == 1024) ? A1 : (wave < 2 ? A1 : A2);
    const int kcA0 = (wave * NC) & 31;
    const int kcW0 = wave * NC;
    const unsigned short* ap = Af + ((size_t)(g * 4) * 32 + kcA0) * 512 + lane * 8;
    const unsigned short* bp = W + ((size_t)(ug * KC + kcW0) * 4) * 512 + lane * 8;

    f32x4 acc[4][4];
#pragma unroll
    for (int i = 0; i < 4; ++i)
#pragma unroll
        for (int j = 0; j < 4; ++j) acc[i][j] = (f32x4){0.f, 0.f, 0.f, 0.f};

    short8 aS[4][4], bS[4][4];
    auto LD = [&](int s, int cc) {
#pragma unroll
        for (int mi = 0; mi < 4; ++mi)
            aS[s][mi] = *(const short8*)(ap + mi * 16384 + cc * 512);
#pragma unroll
        for (int gt = 0; gt < 4; ++gt)
            bS[s][gt] = *(const short8*)(bp + (cc * 4 + gt) * 512);
    };
    auto MM = [&](int s) {
#pragma unroll
        for (int mi = 0; mi < 4; ++mi)
#pragma unroll
            for (int gt = 0; gt < 4; ++gt)
                acc[mi][gt] = __builtin_amdgcn_mfma_f32_16x16x32_bf16(
                    aS[s][mi], bS[s][gt], acc[mi][gt], 0, 0, 0);
    };

    LD(0, 0); LD(1, 1); LD(2, 2); LD(3, 3);
#pragma unroll
    for (int cc = 0; cc < NC; cc += 4) {
        MM(0); LD(0, cc + 4);    // tail iters overrun into guard memory
        MM(1); LD(1, cc + 5);
        MM(2); LD(2, cc + 6);
        MM(3); LD(3, cc + 7);
    }

    // ---- K-split reduction through LDS ----
    const int q = lane >> 4;
    const int m = lane & 15;
    float* Tw = (wave & 1) ? T1 : T0;
    if (wave < 2) {
#pragma unroll
        for (int mi = 0; mi < 4; ++mi)
#pragma unroll
            for (int gt = 0; gt < 4; ++gt)
#pragma unroll
                for (int r = 0; r < 4; ++r)
                    Tw[(mi * 16 + q * 4 + r) * 68 + gt * 16 + m] = acc[mi][gt][r];
    }
    __syncthreads();
    if (wave >= 2) {
#pragma unroll
        for (int mi = 0; mi < 4; ++mi)
#pragma unroll
            for (int gt = 0; gt < 4; ++gt)
#pragma unroll
                for (int r = 0; r < 4; ++r)
                    Tw[(mi * 16 + q * 4 + r) * 68 + gt * 16 + m] += acc[mi][gt][r];
    }
    __syncthreads();

    // ---- epilogue: thread owns (row = tid>>2, units u0..u0+3) ----
    const int lrow = tid >> 2;
    const int uq   = tid & 3;
    const int br   = mb + lrow;
    const int u0   = ub + uq * 4;
    const int toff = lrow * 68 + uq * 4;

    auto gate4 = [&](int gofs) -> float4 {
        float4 a = *(const float4*)(T0 + toff + gofs);
        float4 b = *(const float4*)(T1 + toff + gofs);
        return make_float4(a.x + b.x, a.y + b.y, a.z + b.z, a.w + b.w);
    };
    float4 GI = gate4(0), GF = gate4(16), GG = gate4(32), GO = gate4(48);
    float4 bI = *(const float4*)(bias + u0);
    float4 bF = *(const float4*)(bias + 1024 + u0);
    float4 bG = *(const float4*)(bias + 2048 + u0);
    float4 bO = *(const float4*)(bias + 3072 + u0);
    float4 wI = {0,0,0,0}, wF = {0,0,0,0}, wG = {0,0,0,0}, wO = {0,0,0,0};
    float xv = 0.f;
    if (xvec) {
        xv = xvec[br * xstride];
        wI = *(const float4*)(Wx + u0);
        wF = *(const float4*)(Wx + 1024 + u0);
        wG = *(const float4*)(Wx + 2048 + u0);
        wO = *(const float4*)(Wx + 3072 + u0);
    }
    float4 cc = *(const float4*)(c + (size_t)br * 1024 + u0);

    auto cellc = [&](float gi, float gf, float gg, float go, float cold, float& hO) -> float {
        float i = sigmoidf_(gi);
        float f = sigmoidf_(gf);
        float o = sigmoidf_(go);
        float cn = f * cold + i * tanhf_(gg);
        hO = o * tanhf_(cn);
        return cn;
    };
    float h0v, h1v, h2v, h3v;
    float4 cn;
    cn.x = cellc(GI.x + bI.x + xv * wI.x, GF.x + bF.x + xv * wF.x,
                 GG.x + bG.x + xv * wG.x, GO.x + bO.x + xv * wO.x, cc.x, h0v);
    cn.y = cellc(GI.y + bI.y + xv * wI.y, GF.y + bF.y + xv * wF.y,
                 GG.y + bG.y + xv * wG.y, GO.y + bO.y + xv * wO.y, cc.y, h1v);
    cn.z = cellc(GI.z + bI.z + xv * wI.z, GF.z + bF.z + xv * wF.z,
                 GG.z + bG.z + xv * wG.z, GO.z + bO.z + xv * wO.z, cc.z, h2v);
    cn.w = cellc(GI.w + bI.w + xv * wI.w, GF.w + bF.w + xv * wF.w,
                 GG.w + bG.w + xv * wG.w, GO.w + bO.w + xv * wO.w, cc.w, h3v);
    *(float4*)(c + (size_t)br * 1024 + u0) = cn;

    // packed h store: hP[rg][kc][q*16+m][j]
    {
        const int rg = br >> 4, ml = br & 15;
        const int kc = u0 >> 5, qq = (u0 >> 3) & 3, jo = u0 & 7;
        ushort4 hu;
        hu.x = f2bf(h0v); hu.y = f2bf(h1v); hu.z = f2bf(h2v); hu.w = f2bf(h3v);
        *(ushort4*)(hout + ((size_t)(rg * 32 + kc) * 64 + qq * 16 + ml) * 8 + jo) = hu;
    }

    if (fcW) {
        float4 fw = *(const float4*)(fcW + u0);
        float fcp = h0v * fw.x + h1v * fw.y + h2v * fw.z + h3v * fw.w;
        red[uq * 64 + lrow] = fcp;
        __syncthreads();
        if (tid < 64) {
            float s = red[tid] + red[64 + tid] + red[128 + tid] + red[192 + tid];
            if (ub == 0) s += fcb[0];
            atomicAdd(yout + (size_t)(mb + tid) * 96, s);
        }
    }
}

// Persistent kernel: whole encoder (337 pipelined steps) + decoder (96 x 2
// phases) with device-scope grid barriers between dependent phases.
// 512 blocks x 256 threads, 2 blocks/CU -> all co-resident.
__global__ __launch_bounds__(256, 2) void k_persist(
    const float* __restrict__ x,
    const float* __restrict__ eWih0, const float* __restrict__ eb0,
    const unsigned short* __restrict__ Wenc0,
    const unsigned short* __restrict__ Wenc1, const float* __restrict__ eb1,
    const float* __restrict__ dWih0, const float* __restrict__ db0,
    const unsigned short* __restrict__ Wdec0,
    const unsigned short* __restrict__ Wdec1, const float* __restrict__ db1,
    const float* __restrict__ fcW, const float* __restrict__ fcb,
    unsigned short* h0a, unsigned short* h0b,
    unsigned short* h1a, unsigned short* h1b,
    float* c0, float* c1,
    float* out,
    unsigned* bar)
{
    __shared__ float smem[2 * 64 * 68 + 4 * 64];
    unsigned short* h0[2] = {h0a, h0b};
    unsigned short* h1[2] = {h1a, h1b};
    const int blk = blockIdx.x;
    unsigned* cnt = bar;
    unsigned* gen = bar + 32;   // separate cache line

    // ---- encoder: L0 step t || L1 step t-1 ----
    for (int t = 0; t <= 336; ++t) {
        if (blk < 256) {
            if (t < 336)
                lstm_tile<1024>(smem, blk, h0[(t + 1) & 1], nullptr, Wenc0, eb0,
                                x + t, 336, eWih0, c0, h0[t & 1],
                                nullptr, nullptr, nullptr);
        } else {
            const int u = t - 1;
            if (u >= 0)
                lstm_tile<2048>(smem, blk - 256, h0[u & 1], h1[(u + 1) & 1], Wenc1, eb1,
                                nullptr, 0, nullptr, c1, h1[u & 1],
                                nullptr, nullptr, nullptr);
        }
        gridbar(cnt, gen, 512);
    }

    // ---- decoder: per step, phase A (cell0) then phase B (cell1 + fc) ----
    for (int s = 0; s < 96; ++s) {
        if (blk < 256) {
            const float* xv = (s == 0) ? (x + 335) : (out + (s - 1));
            const int xs = (s == 0) ? 336 : 96;
            lstm_tile<1024>(smem, blk, h0[(s + 1) & 1], nullptr, Wdec0, db0,
                            xv, xs, dWih0, c0, h0[s & 1],
                            nullptr, nullptr, nullptr);
        }
        gridbar(cnt, gen, 512);
        if (blk >= 256) {
            lstm_tile<2048>(smem, blk - 256, h0[s & 1], h1[(s + 1) & 1], Wdec1, db1,
                            nullptr, 0, nullptr, c1, h1[s & 1],
                            fcW, fcb, out + s);
        }
        gridbar(cnt, gen, 512);
    }
}

// ---- prep: pack fp32 weights into WP fragment order (bf16) ----
template<int K>
__global__ void k_packW(const float* __restrict__ srcA, const float* __restrict__ srcB,
                        unsigned short* __restrict__ dst)
{
    constexpr int KC = K / 32;
    const int total = 4096 * K / 8;
    const int du = blockIdx.x * blockDim.x + threadIdx.x;
    if (du >= total) return;
    const int lane = du & 63;
    int rest = du >> 6;
    const int gate = rest & 3; rest >>= 2;
    const int kc = rest % KC;
    const int ug = rest / KC;
    const int q = lane >> 4, m = lane & 15;
    const int row = gate * 1024 + ug * 16 + m;
    const int k = kc * 32 + q * 8;
    const float* s;
    if (K == 2048 && k >= 1024) s = srcB + (size_t)row * 1024 + (k - 1024);
    else                        s = srcA + (size_t)row * 1024 + k;
    const float4 v0 = *(const float4*)(s);
    const float4 v1 = *(const float4*)(s + 4);
    short8 o;
    o[0] = (short)f2bf(v0.x); o[1] = (short)f2bf(v0.y);
    o[2] = (short)f2bf(v0.z); o[3] = (short)f2bf(v0.w);
    o[4] = (short)f2bf(v1.x); o[5] = (short)f2bf(v1.y);
    o[6] = (short)f2bf(v1.z); o[7] = (short)f2bf(v1.w);
    *(short8*)(dst + (size_t)du * 8) = o;
}

extern "C" void kernel_launch(void* const* d_in, const int* in_sizes, int n_in,
                              void* d_out, int out_size, void* d_ws, size_t ws_size,
                              hipStream_t stream)
{
    const float* x     = (const float*)d_in[0];
    const float* eWih0 = (const float*)d_in[1];
    const float* eWhh0 = (const float*)d_in[2];
    const float* eb0   = (const float*)d_in[3];
    const float* eWih1 = (const float*)d_in[4];
    const float* eWhh1 = (const float*)d_in[5];
    const float* eb1   = (const float*)d_in[6];
    const float* dWih0 = (const float*)d_in[7];
    const float* dWhh0 = (const float*)d_in[8];
    const float* db0   = (const float*)d_in[9];
    const float* dWih1 = (const float*)d_in[10];
    const float* dWhh1 = (const float*)d_in[11];
    const float* db1   = (const float*)d_in[12];
    const float* fcW   = (const float*)d_in[13];
    const float* fcb   = (const float*)d_in[14];
    float* out = (float*)d_out;

    char* ws = (char*)d_ws;
    size_t off = 0;
    auto walloc = [&](size_t bytes) -> void* {
        void* p = ws + off;
        off = (off + bytes + 255) & ~(size_t)255;
        return p;
    };
    unsigned short* Wenc0 = (unsigned short*)walloc((size_t)4096 * 1024 * 2 + 32768);
    unsigned short* Wenc1 = (unsigned short*)walloc((size_t)4096 * 2048 * 2 + 32768);
    unsigned short* Wdec0 = (unsigned short*)walloc((size_t)4096 * 1024 * 2 + 32768);
    unsigned short* Wdec1 = (unsigned short*)walloc((size_t)4096 * 2048 * 2 + 32768);
    const size_t STATE = (size_t)4 * 524288 + (size_t)2 * 1048576;
    char* stateBase = (char*)walloc(STATE + 4096 + 65536);  // + barrier + guard
    unsigned short* h0a = (unsigned short*)(stateBase);
    unsigned short* h0b = (unsigned short*)(stateBase + 524288);
    unsigned short* h1a = (unsigned short*)(stateBase + 2 * 524288);
    unsigned short* h1b = (unsigned short*)(stateBase + 3 * 524288);
    float* c0 = (float*)(stateBase + 4 * 524288);
    float* c1 = (float*)(stateBase + 4 * 524288 + 1048576);
    unsigned* bar = (unsigned*)(stateBase + STATE);

    // zero h/c state + barrier vars; zero output (atomic accumulation target)
    hipMemsetAsync(stateBase, 0, STATE + 4096, stream);
    hipMemsetAsync(d_out, 0, (size_t)out_size * sizeof(float), stream);

    {
        const int n1 = 4096 * 1024 / 8;
        const int n2 = 4096 * 2048 / 8;
        k_packW<1024><<<n1 / 256, 256, 0, stream>>>(eWhh0, nullptr, Wenc0);
        k_packW<1024><<<n1 / 256, 256, 0, stream>>>(dWhh0, nullptr, Wdec0);
        k_packW<2048><<<n2 / 256, 256, 0, stream>>>(eWih1, eWhh1, Wenc1);
        k_packW<2048><<<n2 / 256, 256, 0, stream>>>(dWih1, dWhh1, Wdec1);
    }

    k_persist<<<512, 256, 0, stream>>>(
        x, eWih0, eb0, Wenc0, Wenc1, eb1,
        dWih0, db0, Wdec0, Wdec1, db1,
        fcW, fcb,
        h0a, h0b, h1a, h1b, c0, c1, out, bar);
}

// Round 5
// 9165.167 us; speedup vs baseline: 3.1801x; 3.1801x over previous
//
#include <hip/hip_runtime.h>

typedef short short8 __attribute__((ext_vector_type(8)));
typedef float f32x4 __attribute__((ext_vector_type(4)));

#define SMEM_BYTES (2*64*68*4 + 4*64*4)   // two 64x68 f32 tiles + 4x64 fc-reduce

__device__ __forceinline__ unsigned short f2bf(float x) {
    unsigned int u = __float_as_uint(x);
    u += 0x7FFFu + ((u >> 16) & 1u);   // round-to-nearest-even
    return (unsigned short)(u >> 16);
}

__device__ __forceinline__ float sigmoidf_(float x) {
    return 1.0f / (1.0f + __expf(-x));
}

__device__ __forceinline__ float tanhf_(float x) {
    float ax = fabsf(x);
    float e = __expf(2.0f * ax);
    float t = 1.0f - 2.0f / (e + 1.0f);
    return copysignf(t, x);
}

// ---------------- packed layouts ----------------
// hP  [rg 16][kc 32][lane 64][j 8]  (lane = q*16+m holds h[rg*16+m][kc*32+q*8+j])
// WP  [ug 64][kc K/32][gate 4][lane 64][j 8]
// Every K-loop load is base + lane*16B -> one contiguous 1 KB per instruction.

// One LSTM step tile: 64 batch rows x 16 units (x4 gates).
// 4 waves K-split, 4x4 MFMA register blocking, 4-stage register pipeline
// (needs ~224 VGPRs -> kernels use amdgpu_waves_per_eu(2,2) so the allocator
// doesn't collapse the pipeline; R4 profile showed it clamps to 128 otherwise).
// Prefetch overruns up to 3 chunks past the slice end -> guard memory required.
template<int K>
__device__ __forceinline__ void lstm_tile(
    int idx,
    const unsigned short* __restrict__ A1,   // hP, first K-half
    const unsigned short* __restrict__ A2,   // hP, second K-half (K==2048) or null
    const unsigned short* __restrict__ W,    // WP packed
    const float* __restrict__ bias,          // [4096]
    const float* __restrict__ xvec, int xstride,
    const float* __restrict__ Wx,            // [4096] or null
    float* __restrict__ c,                   // [256,1024] fp32 in-place
    unsigned short* __restrict__ hout,       // hP packed out
    const float* __restrict__ fcW,
    const float* __restrict__ fcb,
    float* __restrict__ yout)
{
    extern __shared__ float smem[];
    float* T0  = smem;                 // 64 x 68
    float* T1  = smem + 64 * 68;
    float* red = smem + 2 * 64 * 68;   // 4 x 64

    constexpr int KS = K / 4;
    constexpr int NC = KS / 32;        // chunks per wave (8 or 16)
    constexpr int KC = K / 32;
    const int tid  = threadIdx.x;
    const int lane = tid & 63;
    const int wave = tid >> 6;
    const int g  = idx >> 6;           // batch group (64 rows)
    const int ug = idx & 63;           // unit group (16 units)
    const int mb = g * 64;
    const int ub = ug * 16;

    const unsigned short* Af = (K == 1024) ? A1 : (wave < 2 ? A1 : A2);
    const int kcA0 = (wave * NC) & 31;
    const int kcW0 = wave * NC;
    const unsigned short* ap = Af + ((size_t)(g * 4) * 32 + kcA0) * 512 + lane * 8;
    const unsigned short* bp = W + ((size_t)(ug * KC + kcW0) * 4) * 512 + lane * 8;

    f32x4 acc[4][4];
#pragma unroll
    for (int i = 0; i < 4; ++i)
#pragma unroll
        for (int j = 0; j < 4; ++j) acc[i][j] = (f32x4){0.f, 0.f, 0.f, 0.f};

    short8 aS[4][4], bS[4][4];
    auto LD = [&](int s, int cc) {
#pragma unroll
        for (int mi = 0; mi < 4; ++mi)
            aS[s][mi] = *(const short8*)(ap + mi * 16384 + cc * 512);
#pragma unroll
        for (int gt = 0; gt < 4; ++gt)
            bS[s][gt] = *(const short8*)(bp + (cc * 4 + gt) * 512);
    };
    auto MM = [&](int s) {
#pragma unroll
        for (int mi = 0; mi < 4; ++mi)
#pragma unroll
            for (int gt = 0; gt < 4; ++gt)
                acc[mi][gt] = __builtin_amdgcn_mfma_f32_16x16x32_bf16(
                    aS[s][mi], bS[s][gt], acc[mi][gt], 0, 0, 0);
    };

    LD(0, 0); LD(1, 1); LD(2, 2); LD(3, 3);
#pragma unroll
    for (int cc = 0; cc < NC; cc += 4) {
        MM(0); LD(0, cc + 4);    // tail iters overrun into guard memory
        MM(1); LD(1, cc + 5);
        MM(2); LD(2, cc + 6);
        MM(3); LD(3, cc + 7);
    }

    // ---- K-split reduction through LDS ----
    const int q = lane >> 4;
    const int m = lane & 15;
    float* Tw = (wave & 1) ? T1 : T0;
    if (wave < 2) {
#pragma unroll
        for (int mi = 0; mi < 4; ++mi)
#pragma unroll
            for (int gt = 0; gt < 4; ++gt)
#pragma unroll
                for (int r = 0; r < 4; ++r)
                    Tw[(mi * 16 + q * 4 + r) * 68 + gt * 16 + m] = acc[mi][gt][r];
    }
    __syncthreads();
    if (wave >= 2) {
#pragma unroll
        for (int mi = 0; mi < 4; ++mi)
#pragma unroll
            for (int gt = 0; gt < 4; ++gt)
#pragma unroll
                for (int r = 0; r < 4; ++r)
                    Tw[(mi * 16 + q * 4 + r) * 68 + gt * 16 + m] += acc[mi][gt][r];
    }
    __syncthreads();

    // ---- epilogue: thread owns (row = tid>>2, units u0..u0+3) ----
    const int lrow = tid >> 2;
    const int uq   = tid & 3;
    const int br   = mb + lrow;
    const int u0   = ub + uq * 4;
    const int toff = lrow * 68 + uq * 4;

    auto gate4 = [&](int gofs) -> float4 {
        float4 a = *(const float4*)(T0 + toff + gofs);
        float4 b = *(const float4*)(T1 + toff + gofs);
        return make_float4(a.x + b.x, a.y + b.y, a.z + b.z, a.w + b.w);
    };
    float4 GI = gate4(0), GF = gate4(16), GG = gate4(32), GO = gate4(48);
    float4 bI = *(const float4*)(bias + u0);
    float4 bF = *(const float4*)(bias + 1024 + u0);
    float4 bG = *(const float4*)(bias + 2048 + u0);
    float4 bO = *(const float4*)(bias + 3072 + u0);
    float4 wI = {0,0,0,0}, wF = {0,0,0,0}, wG = {0,0,0,0}, wO = {0,0,0,0};
    float xv = 0.f;
    if (xvec) {
        xv = xvec[br * xstride];
        wI = *(const float4*)(Wx + u0);
        wF = *(const float4*)(Wx + 1024 + u0);
        wG = *(const float4*)(Wx + 2048 + u0);
        wO = *(const float4*)(Wx + 3072 + u0);
    }
    float4 cc = *(const float4*)(c + (size_t)br * 1024 + u0);

    auto cellc = [&](float gi, float gf, float gg, float go, float cold, float& hO) -> float {
        float i = sigmoidf_(gi);
        float f = sigmoidf_(gf);
        float o = sigmoidf_(go);
        float cn = f * cold + i * tanhf_(gg);
        hO = o * tanhf_(cn);
        return cn;
    };
    float h0v, h1v, h2v, h3v;
    float4 cn;
    cn.x = cellc(GI.x + bI.x + xv * wI.x, GF.x + bF.x + xv * wF.x,
                 GG.x + bG.x + xv * wG.x, GO.x + bO.x + xv * wO.x, cc.x, h0v);
    cn.y = cellc(GI.y + bI.y + xv * wI.y, GF.y + bF.y + xv * wF.y,
                 GG.y + bG.y + xv * wG.y, GO.y + bO.y + xv * wO.y, cc.y, h1v);
    cn.z = cellc(GI.z + bI.z + xv * wI.z, GF.z + bF.z + xv * wF.z,
                 GG.z + bG.z + xv * wG.z, GO.z + bO.z + xv * wO.z, cc.z, h2v);
    cn.w = cellc(GI.w + bI.w + xv * wI.w, GF.w + bF.w + xv * wF.w,
                 GG.w + bG.w + xv * wG.w, GO.w + bO.w + xv * wO.w, cc.w, h3v);
    *(float4*)(c + (size_t)br * 1024 + u0) = cn;

    // packed h store: hP[rg][kc][q*16+m][j]
    {
        const int rg = br >> 4, ml = br & 15;
        const int kc = u0 >> 5, qq = (u0 >> 3) & 3, jo = u0 & 7;
        ushort4 hu;
        hu.x = f2bf(h0v); hu.y = f2bf(h1v); hu.z = f2bf(h2v); hu.w = f2bf(h3v);
        *(ushort4*)(hout + ((size_t)(rg * 32 + kc) * 64 + qq * 16 + ml) * 8 + jo) = hu;
    }

    if (fcW) {
        float4 fw = *(const float4*)(fcW + u0);
        float fcp = h0v * fw.x + h1v * fw.y + h2v * fw.z + h3v * fw.w;
        red[uq * 64 + lrow] = fcp;
        __syncthreads();
        if (tid < 64) {
            float s = red[tid] + red[64 + tid] + red[128 + tid] + red[192 + tid];
            if (ub == 0) s += fcb[0];
            atomicAdd(yout + (size_t)(mb + tid) * 96, s);
        }
    }
}

// Encoder: blocks 0..255 layer0 step t; 256..511 layer1 step t-1 (pipelined).
__global__ __launch_bounds__(256)
__attribute__((amdgpu_waves_per_eu(2, 2)))
void k_enc_step(
    int t,
    const float* __restrict__ x,
    const float* __restrict__ Wih0, const float* __restrict__ b0,
    const unsigned short* __restrict__ Wenc0,
    const unsigned short* __restrict__ Wenc1, const float* __restrict__ b1,
    unsigned short* h0a, unsigned short* h0b,
    unsigned short* h1a, unsigned short* h1b,
    float* c0, float* c1)
{
    unsigned short* h0[2] = {h0a, h0b};
    unsigned short* h1[2] = {h1a, h1b};
    const int blk = blockIdx.x;
    if (blk < 256) {
        if (t >= 336) return;
        lstm_tile<1024>(blk, h0[(t + 1) & 1], nullptr, Wenc0, b0,
                        x + t, 336, Wih0, c0, h0[t & 1],
                        nullptr, nullptr, nullptr);
    } else {
        const int u = t - 1;
        if (u < 0) return;
        lstm_tile<2048>(blk - 256, h0[u & 1], h1[(u + 1) & 1], Wenc1, b1,
                        nullptr, 0, nullptr, c1, h1[u & 1],
                        nullptr, nullptr, nullptr);
    }
}

__global__ __launch_bounds__(256)
__attribute__((amdgpu_waves_per_eu(2, 2)))
void k_dec0(
    int s,
    const float* __restrict__ x,
    const float* __restrict__ dout,
    const float* __restrict__ Wih0, const float* __restrict__ b0,
    const unsigned short* __restrict__ Wdec0,
    unsigned short* h0a, unsigned short* h0b, float* c0)
{
    unsigned short* h0[2] = {h0a, h0b};
    const float* xv; int xs;
    if (s == 0) { xv = x + 335; xs = 336; }
    else        { xv = dout + (s - 1); xs = 96; }
    lstm_tile<1024>(blockIdx.x, h0[(s + 1) & 1], nullptr, Wdec0, b0,
                    xv, xs, Wih0, c0, h0[s & 1],
                    nullptr, nullptr, nullptr);
}

__global__ __launch_bounds__(256)
__attribute__((amdgpu_waves_per_eu(2, 2)))
void k_dec1(
    int s,
    const unsigned short* __restrict__ Wdec1, const float* __restrict__ b1,
    unsigned short* h0a, unsigned short* h0b,
    unsigned short* h1a, unsigned short* h1b,
    float* c1,
    const float* __restrict__ fcW, const float* __restrict__ fcb,
    float* __restrict__ dout)
{
    unsigned short* h0[2] = {h0a, h0b};
    unsigned short* h1[2] = {h1a, h1b};
    lstm_tile<2048>(blockIdx.x, h0[s & 1], h1[(s + 1) & 1], Wdec1, b1,
                    nullptr, 0, nullptr, c1, h1[s & 1],
                    fcW, fcb, dout + s);
}

// ---- prep: pack fp32 weights into WP fragment order (bf16) ----
template<int K>
__global__ void k_packW(const float* __restrict__ srcA, const float* __restrict__ srcB,
                        unsigned short* __restrict__ dst)
{
    constexpr int KC = K / 32;
    const int total = 4096 * K / 8;
    const int du = blockIdx.x * blockDim.x + threadIdx.x;
    if (du >= total) return;
    const int lane = du & 63;
    int rest = du >> 6;
    const int gate = rest & 3; rest >>= 2;
    const int kc = rest % KC;
    const int ug = rest / KC;
    const int q = lane >> 4, m = lane & 15;
    const int row = gate * 1024 + ug * 16 + m;
    const int k = kc * 32 + q * 8;
    const float* s;
    if (K == 2048 && k >= 1024) s = srcB + (size_t)row * 1024 + (k - 1024);
    else                        s = srcA + (size_t)row * 1024 + k;
    const float4 v0 = *(const float4*)(s);
    const float4 v1 = *(const float4*)(s + 4);
    short8 o;
    o[0] = (short)f2bf(v0.x); o[1] = (short)f2bf(v0.y);
    o[2] = (short)f2bf(v0.z); o[3] = (short)f2bf(v0.w);
    o[4] = (short)f2bf(v1.x); o[5] = (short)f2bf(v1.y);
    o[6] = (short)f2bf(v1.z); o[7] = (short)f2bf(v1.w);
    *(short8*)(dst + (size_t)du * 8) = o;
}

extern "C" void kernel_launch(void* const* d_in, const int* in_sizes, int n_in,
                              void* d_out, int out_size, void* d_ws, size_t ws_size,
                              hipStream_t stream)
{
    const float* x     = (const float*)d_in[0];
    const float* eWih0 = (const float*)d_in[1];
    const float* eWhh0 = (const float*)d_in[2];
    const float* eb0   = (const float*)d_in[3];
    const float* eWih1 = (const float*)d_in[4];
    const float* eWhh1 = (const float*)d_in[5];
    const float* eb1   = (const float*)d_in[6];
    const float* dWih0 = (const float*)d_in[7];
    const float* dWhh0 = (const float*)d_in[8];
    const float* db0   = (const float*)d_in[9];
    const float* dWih1 = (const float*)d_in[10];
    const float* dWhh1 = (const float*)d_in[11];
    const float* db1   = (const float*)d_in[12];
    const float* fcW   = (const float*)d_in[13];
    const float* fcb   = (const float*)d_in[14];
    float* out = (float*)d_out;

    char* ws = (char*)d_ws;
    size_t off = 0;
    auto walloc = [&](size_t bytes) -> void* {
        void* p = ws + off;
        off = (off + bytes + 255) & ~(size_t)255;
        return p;
    };
    unsigned short* Wenc0 = (unsigned short*)walloc((size_t)4096 * 1024 * 2 + 32768);
    unsigned short* Wenc1 = (unsigned short*)walloc((size_t)4096 * 2048 * 2 + 32768);
    unsigned short* Wdec0 = (unsigned short*)walloc((size_t)4096 * 1024 * 2 + 32768);
    unsigned short* Wdec1 = (unsigned short*)walloc((size_t)4096 * 2048 * 2 + 32768);
    const size_t STATE = (size_t)4 * 524288 + (size_t)2 * 1048576;
    char* stateBase = (char*)walloc(STATE + 65536);   // + guard for prefetch overrun
    unsigned short* h0a = (unsigned short*)(stateBase);
    unsigned short* h0b = (unsigned short*)(stateBase + 524288);
    unsigned short* h1a = (unsigned short*)(stateBase + 2 * 524288);
    unsigned short* h1b = (unsigned short*)(stateBase + 3 * 524288);
    float* c0 = (float*)(stateBase + 4 * 524288);
    float* c1 = (float*)(stateBase + 4 * 524288 + 1048576);

    hipMemsetAsync(stateBase, 0, STATE, stream);
    hipMemsetAsync(d_out, 0, (size_t)out_size * sizeof(float), stream);

    {
        const int n1 = 4096 * 1024 / 8;
        const int n2 = 4096 * 2048 / 8;
        k_packW<1024><<<n1 / 256, 256, 0, stream>>>(eWhh0, nullptr, Wenc0);
        k_packW<1024><<<n1 / 256, 256, 0, stream>>>(dWhh0, nullptr, Wdec0);
        k_packW<2048><<<n2 / 256, 256, 0, stream>>>(eWih1, eWhh1, Wenc1);
        k_packW<2048><<<n2 / 256, 256, 0, stream>>>(dWih1, dWhh1, Wdec1);
    }

    for (int t = 0; t <= 336; ++t) {
        k_enc_step<<<512, 256, SMEM_BYTES, stream>>>(t, x, eWih0, eb0, Wenc0, Wenc1, eb1,
                                                     h0a, h0b, h1a, h1b, c0, c1);
    }
    for (int s = 0; s < 96; ++s) {
        k_dec0<<<256, 256, SMEM_BYTES, stream>>>(s, x, out, dWih0, db0, Wdec0, h0a, h0b, c0);
        k_dec1<<<256, 256, SMEM_BYTES, stream>>>(s, Wdec1, db1, h0a, h0b, h1a, h1b, c1,
                                                 fcW, fcb, out);
    }
}